// Round 15
// baseline (173.432 us; speedup 1.0000x reference)
//
#include <hip/hip_runtime.h>
#include <cstdint>

// Reference geometry (fixed problem)
constexpr int B_ = 4, H_ = 8, D_ = 64, L_ = 4096;
constexpr int BH = B_ * H_;          // 32
constexpr int U_PART = 25;           // FACTOR * ceil(log(64))
constexpr int TOPU = 45;             // FACTOR * ceil(log(4096))
constexpr int CHUNK = 128;           // keys per update chunk (LDS-staged)
constexpr int NCH = L_ / CHUNK;      // 32 chunks
constexpr int PSTRIDE = 68;          // acc[64], max, sum, pad to 16B-aligned stride

#define JAX_THREEFRY_PARTITIONABLE 1

typedef float f4v __attribute__((ext_vector_type(4)));

// ---------------- Threefry-2x32 (exact JAX semantics) ----------------
__host__ __device__ inline void tf2x32(uint32_t k0, uint32_t k1,
                                       uint32_t x0, uint32_t x1,
                                       uint32_t& y0, uint32_t& y1) {
  const uint32_t ks2 = k0 ^ k1 ^ 0x1BD11BDAu;
  uint32_t v0 = x0 + k0, v1 = x1 + k1;
#define RND(r) { v0 += v1; v1 = (v1 << (r)) | (v1 >> (32 - (r))); v1 ^= v0; }
  RND(13) RND(15) RND(26) RND(6)
  v0 += k1; v1 += ks2 + 1u;
  RND(17) RND(29) RND(16) RND(24)
  v0 += ks2; v1 += k0 + 2u;
  RND(13) RND(15) RND(26) RND(6)
  v0 += k0; v1 += k1 + 3u;
  RND(17) RND(29) RND(16) RND(24)
  v0 += k1; v1 += ks2 + 4u;
  RND(13) RND(15) RND(26) RND(6)
  v0 += ks2; v1 += k0 + 5u;
#undef RND
  y0 = v0; y1 = v1;
}

// ---------------- prep: k transpose+scale + threefry idx ----------------
__global__ __launch_bounds__(256) void prep_kernel(
    const float* __restrict__ k, float* __restrict__ kt,
    int* __restrict__ idx, uint32_t k2a, uint32_t k2b) {
  const int bh = blockIdx.y;
  const int t = threadIdx.x;
  // threefry: 50 indices per block (2048 blocks x 50 = 102400 = L*25)
#if JAX_THREEFRY_PARTITIONABLE
  {
    const int bid = bh * 64 + blockIdx.x;
    if (t < 50) {
      uint32_t y0, y1;
      const uint32_t i = (uint32_t)(bid * 50 + t);
      tf2x32(k2a, k2b, 0u, i, y0, y1);
      idx[bid * 50 + t] = (int)((y0 ^ y1) & 4095u);
    }
  }
#else
  {
    const int bid = bh * 64 + blockIdx.x;
    const int half = (L_ * U_PART) / 2;   // 51200
    if (t < 25) {
      uint32_t y0, y1;
      const int j = bid * 25 + t;
      tf2x32(k2a, k2b, (uint32_t)j, (uint32_t)(j + half), y0, y1);
      idx[j] = (int)(y0 & 4095u);
      idx[j + half] = (int)(y1 & 4095u);
    }
  }
#endif
  // k transpose + scale (1/64), float4 global both sides
  const int l0 = blockIdx.x * 64;
  __shared__ float tile[64][65];
  const float* s = k + (size_t)bh * D_ * L_ + l0;
  float* d = kt + (size_t)bh * L_ * D_;
  const int rhi = t >> 4, rlo = t & 15;
#pragma unroll
  for (int i = 0; i < 4; i++) {
    const int dd = i * 16 + rhi;
    float4 x = *(const float4*)&s[(size_t)dd * L_ + 4 * rlo];
    tile[dd][4 * rlo + 0] = x.x * (1.0f / 64.0f);
    tile[dd][4 * rlo + 1] = x.y * (1.0f / 64.0f);
    tile[dd][4 * rlo + 2] = x.z * (1.0f / 64.0f);
    tile[dd][4 * rlo + 3] = x.w * (1.0f / 64.0f);
  }
  __syncthreads();
#pragma unroll
  for (int i = 0; i < 4; i++) {
    const int ll = i * 16 + rhi;
    float4 o;
    o.x = tile[4 * rlo + 0][ll];
    o.y = tile[4 * rlo + 1][ll];
    o.z = tile[4 * rlo + 2][ll];
    o.w = tile[4 * rlo + 3][ll];
    *(float4*)&d[(size_t)(l0 + ll) * D_ + 4 * rlo] = o;
  }
}

// ---------------- DPP 16-lane butterfly helper (VALU, no DS pipe) ----------------
__device__ __forceinline__ float dpp_bcast_add16(float x) {
  int xi;
  xi = __builtin_amdgcn_mov_dpp(__float_as_int(x), 0x140, 0xF, 0xF, true);
  x += __int_as_float(xi);
  xi = __builtin_amdgcn_mov_dpp(__float_as_int(x), 0x141, 0xF, 0xF, true);
  x += __int_as_float(xi);
  xi = __builtin_amdgcn_mov_dpp(__float_as_int(x), 0x4E, 0xF, 0xF, true);
  x += __int_as_float(xi);
  xi = __builtin_amdgcn_mov_dpp(__float_as_int(x), 0xB1, 0xF, 0xF, true);
  x += __int_as_float(xi);
  return x;
}

// ---------------- FUSED: M-score blocks (latency-bound) + cumsum blocks (BW) ----------------
// 2560 blocks of 1024 threads; every 5th block (bid%5==4) runs the v-cumsum for
// 4 rows with NONTEMPORAL loads/stores (don't evict kt from L2). The other 2048
// are m-blocks with an exact XCD-preserving (bh, l-tile) mapping.
__global__ __launch_bounds__(1024) void m_cumsum_kernel(
    const float* __restrict__ qraw, const float* __restrict__ kt,
    const int* __restrict__ idx, const float* __restrict__ vraw,
    float* __restrict__ M, float* __restrict__ out) {
  const int bid = blockIdx.x;
  const int t = threadIdx.x;
  __shared__ float qs[64][65];
  __shared__ float wtot[4][4];
  if (bid % 5 == 4) {
    // ---- cumsum path: 4 rows (bh*64+d) per block, nontemporal streaming ----
    const int slot = bid / 5;            // 0..511
    const int sg = t >> 8;               // sub-group 0..3, 256 threads each
    const int t2 = t & 255;
    const int row = slot * 4 + sg;       // 0..2047 = bh*D + d
    const float* src = vraw + (size_t)row * L_;
    float* dst = out + (size_t)row * L_;
    float vals[16];
    const f4v* s4 = (const f4v*)(src + t2 * 16);
#pragma unroll
    for (int i = 0; i < 4; i++) {
      f4v x = __builtin_nontemporal_load(&s4[i]);
      vals[4 * i + 0] = x.x; vals[4 * i + 1] = x.y;
      vals[4 * i + 2] = x.z; vals[4 * i + 3] = x.w;
    }
    float run = 0.0f;
#pragma unroll
    for (int i = 0; i < 16; i++) { run += vals[i] * (1.0f / 64.0f); vals[i] = run; }
    float x = run;
#pragma unroll
    for (int off = 1; off < 64; off <<= 1) {
      float y = __shfl_up(x, off, 64);
      if ((t2 & 63) >= off) x += y;
    }
    if ((t2 & 63) == 63) wtot[sg][t2 >> 6] = x;
    __syncthreads();
    float woff = 0.0f;
    for (int w = 0; w < (t2 >> 6); w++) woff += wtot[sg][w];
    const float excl = x - run + woff;
#pragma unroll
    for (int i = 0; i < 16; i++) vals[i] += excl;
    f4v* d4 = (f4v*)(dst + t2 * 16);
#pragma unroll
    for (int i = 0; i < 4; i++) {
      f4v o = {vals[4 * i], vals[4 * i + 1], vals[4 * i + 2], vals[4 * i + 3]};
      __builtin_nontemporal_store(o, &d4[i]);
    }
    return;
  }
  // ---- M path: 64 l's per block, one l per 16-lane group, one chain/thread ----
  // XCD-preserving mapping: per mod-40 group each mod-8 class has 4 m-blocks.
  const int xcd = bid & 7;
  const int c = bid % 40;
  const int rbad_tbl[8] = {24, 9, 34, 19, 4, 29, 14, 39};  // the cumsum residue
  const int rank = (c >> 3) - (rbad_tbl[xcd] < c ? 1 : 0);
  const int o = (bid / 40) * 4 + rank;        // 0..255 per XCD
  const int bh = xcd * 4 + (o >> 6);
  const int l0 = (o & 63) * 64;
  const float* ktb = kt + (size_t)bh * L_ * D_;
  {
    const float* s = qraw + (size_t)bh * D_ * L_ + l0;
    const int w = t >> 6, lane = t & 63;
#pragma unroll
    for (int j = 0; j < 4; j++) {
      const int d = j * 16 + w;
      qs[lane][d] = s[(size_t)d * L_ + lane] * (1.0f / 512.0f);
    }
  }
  __syncthreads();
  const int grp = t >> 4, gl = t & 15;         // 64 groups, one l each
  const int l = l0 + grp;
  const float4 ql = *(const float4*)&qs[grp][4 * gl];
  const int* ip = idx + (size_t)l * U_PART;
  float mx = -INFINITY, sm = 0.0f;
#pragma unroll 5
  for (int s2 = 0; s2 < U_PART; s2++) {
    const int ki = ip[s2];
    float4 kk = *(const float4*)(ktb + (size_t)ki * D_ + gl * 4);
    float p = ql.x * kk.x + ql.y * kk.y + ql.z * kk.z + ql.w * kk.w;
    p = dpp_bcast_add16(p);
    mx = fmaxf(mx, p);
    sm += p;
  }
  if (gl == 0) M[bh * L_ + l] = mx - sm * (1.0f / 4096.0f);
}

// ---------------- top-45 per (b,h) + qsel gather, SORTED DESC by index ----------------
__global__ __launch_bounds__(256) void topk_kernel(const float* __restrict__ M,
                                                   const float* __restrict__ qraw,
                                                   int* __restrict__ ssel_g,
                                                   float* __restrict__ qsel) {
  const int bh = blockIdx.x, t = threadIdx.x;
  const int w = t >> 6, lane = t & 63;
  const float* Mb = M + (size_t)bh * L_;
  const int base = w * 1024 + lane;
  uint32_t v[16];
#pragma unroll
  for (int j = 0; j < 16; j++) {
    uint32_t b = __float_as_uint(Mb[base + j * 64]);
    v[j] = b ^ ((b & 0x80000000u) ? 0xFFFFFFFFu : 0x80000000u);
  }
  __shared__ unsigned long long red[4];
  __shared__ int picks[TOPU];
  __shared__ int ssorted[TOPU];
  for (int it = 0; it < TOPU; it++) {
    unsigned long long best = 0ull;
#pragma unroll
    for (int j = 0; j < 16; j++) {
      unsigned long long key = ((unsigned long long)v[j] << 32)
                             | (uint32_t)(L_ - 1 - (base + j * 64));
      best = (key > best) ? key : best;
    }
#pragma unroll
    for (int off = 32; off; off >>= 1) {
      unsigned long long o = __shfl_xor(best, off, 64);
      best = (o > best) ? o : best;
    }
    if (lane == 0) red[w] = best;
    __syncthreads();
    unsigned long long g = red[0];
    if (red[1] > g) g = red[1];
    if (red[2] > g) g = red[2];
    if (red[3] > g) g = red[3];
    const int bi = L_ - 1 - (int)(g & 0xFFFFFFFFu);
    if (t == 0) picks[it] = bi;
    if ((bi >> 10) == w && (bi & 63) == lane) {
      const int slot = (bi >> 6) & 15;
#pragma unroll
      for (int j = 0; j < 16; j++) if (slot == j) v[j] = 0u;
    }
    __syncthreads();
  }
  if (t < TOPU) {
    int my = picks[t];
    int rank = 0;
    for (int j = 0; j < TOPU; j++) rank += (picks[j] > my);
    ssorted[rank] = my;
  }
  __syncthreads();
  if (t < TOPU) ssel_g[bh * TOPU + t] = ssorted[t];
  // gather selected q rows (scaled): qsel[bh][r][d] = q[bh, d, sel_r] / 512
  const float* qb = qraw + (size_t)bh * D_ * L_;
  for (int e = t; e < TOPU * 64; e += 256) {
    const int r = e >> 6, d = e & 63;
    qsel[((size_t)bh * TOPU + r) * 64 + e % 64] =
        qb[(size_t)d * L_ + ssorted[r]] * (1.0f / 512.0f);
  }
}

// ---------------- update phase 1: register-tiled GEMM per (bh, chunk-pair) ----------------
// Q from qsel (coalesced); K staged linear [d][key] from raw k; V staged [d][key]
// with granule-XOR swizzle from raw v. PV dots along the key axis. XCD-swizzled.
__global__ __launch_bounds__(256) void update_partial(const float* __restrict__ qsel,
                                                      const float* __restrict__ kraw,
                                                      const float* __restrict__ vraw,
                                                      const int* __restrict__ ssel_g,
                                                      float* __restrict__ part) {
  const int xcd = blockIdx.x & 7;
  const int slot = blockIdx.x >> 3;   // 0..63
  const int bh = xcd * 4 + (slot >> 4);
  const int ch0 = slot & 15;
  const int t = threadIdx.x;
  const int w = t >> 6, lane = t & 63;
  const int kl = lane & 15, rg = lane >> 4;

  __shared__ float kv[CHUNK * 64];    // 32KB: kS[d][128] linear, then vS[d][128] swizzled
  __shared__ float qs[48 * 68];       // padded stride 68
  __shared__ float eS[48 * 132];      // padded stride 132
  __shared__ int ssel[48];

  if (t < 48) ssel[t] = (t < TOPU) ? ssel_g[bh * TOPU + t] : -1;
  __syncthreads();

  // stage Q from qsel: 48 rows x 64 d (rows 45..47 zero)
#pragma unroll
  for (int j = 0; j < 3; j++) {
    int it = t + 256 * j;             // 0..767
    int rr = it >> 4, dc = it & 15;
    float4 qv = make_float4(0.f, 0.f, 0.f, 0.f);
    if (rr < TOPU) qv = *(const float4*)&qsel[((size_t)bh * TOPU + rr) * 64 + 4 * dc];
    *(float4*)&qs[rr * 68 + 4 * dc] = qv;
  }

  for (int pass = 0; pass < 2; pass++) {
    const int ch = pass ? (31 - ch0) : ch0;
    const int k0 = ch * CHUNK;
    int lo = 0, hi = TOPU;
    while (lo < hi) { int mid = (lo + hi) >> 1; if (ssel[mid] >= k0) lo = mid + 1; else hi = mid; }
    const int nact = lo;
    if (nact == 0) continue;          // uniform across block

    __syncthreads();
    // stage K: kv[d*128 + key] = kraw[bh, d, k0+key]  (linear, conflict-free)
    const float* kb = kraw + (size_t)bh * D_ * L_ + k0;
#pragma unroll
    for (int j = 0; j < 8; j++) {
      int e4 = 4 * (t + 256 * j);
      int d = e4 >> 7, key = e4 & 127;
      *(float4*)&kv[e4] = *(const float4*)&kb[(size_t)d * L_ + key];
    }
    __syncthreads();

    const int wr0 = 12 * w;
    if (wr0 < nact) {
      float s[3][8];
#pragma unroll
      for (int j = 0; j < 3; j++)
#pragma unroll
        for (int x = 0; x < 8; x++) s[j][x] = 0.f;
#pragma unroll 8
      for (int d = 0; d < 64; d++) {
        float4 ka = *(const float4*)&kv[d * 128 + 4 * kl];
        float4 kb2 = *(const float4*)&kv[d * 128 + 64 + 4 * kl];
#pragma unroll
        for (int j = 0; j < 3; j++) {
          float qd = qs[(wr0 + 3 * rg + j) * 68 + d];
          s[j][0] += qd * ka.x;  s[j][1] += qd * ka.y;
          s[j][2] += qd * ka.z;  s[j][3] += qd * ka.w;
          s[j][4] += qd * kb2.x; s[j][5] += qd * kb2.y;
          s[j][6] += qd * kb2.z; s[j][7] += qd * kb2.w;
        }
      }
#pragma unroll
      for (int j = 0; j < 3; j++) {
        const int R = wr0 + 3 * rg + j;
        const int sel = ssel[R];
        float mx = -INFINITY;
#pragma unroll
        for (int x = 0; x < 8; x++) {
          int kg = k0 + 4 * kl + (x < 4 ? x : 60 + x);   // keys 4kl+{0..3}, 64+4kl+{0..3}
          s[j][x] *= (1.0f / 32768.0f);
          if (kg > sel) s[j][x] = -INFINITY;
          mx = fmaxf(mx, s[j][x]);
        }
        mx = fmaxf(mx, __shfl_xor(mx, 1, 64));
        mx = fmaxf(mx, __shfl_xor(mx, 2, 64));
        mx = fmaxf(mx, __shfl_xor(mx, 4, 64));
        mx = fmaxf(mx, __shfl_xor(mx, 8, 64));
        float e[8], sm = 0.f;
#pragma unroll
        for (int x = 0; x < 8; x++) { e[x] = expf(s[j][x] - mx); sm += e[x]; }
        sm += __shfl_xor(sm, 1, 64);
        sm += __shfl_xor(sm, 2, 64);
        sm += __shfl_xor(sm, 4, 64);
        sm += __shfl_xor(sm, 8, 64);
        *(float4*)&eS[R * 132 + 4 * kl] = make_float4(e[0], e[1], e[2], e[3]);
        *(float4*)&eS[R * 132 + 64 + 4 * kl] = make_float4(e[4], e[5], e[6], e[7]);
        if (kl == 0 && R < nact) {
          float* p = part + ((size_t)(bh * TOPU + R) * NCH + ch) * PSTRIDE;
          p[64] = mx; p[65] = sm;
        }
      }
    }
    __syncthreads();
    // stage V: kv[d*128 + ((kq ^ (d&31))<<2)] = vraw[bh, d, k0+4kq..+3]
    const float* vb = vraw + (size_t)bh * D_ * L_ + k0;
#pragma unroll
    for (int j = 0; j < 8; j++) {
      int e4 = 4 * (t + 256 * j);
      int d = e4 >> 7, kq = (e4 & 127) >> 2;
      float4 vv = *(const float4*)&vb[(size_t)d * L_ + 4 * kq];
      *(float4*)&kv[d * 128 + ((kq ^ (d & 31)) << 2)] = vv;
    }
    __syncthreads();
    if (wr0 < nact) {
      float acc[3][4];
#pragma unroll
      for (int j = 0; j < 3; j++)
#pragma unroll
        for (int x = 0; x < 4; x++) acc[j][x] = 0.f;
      const int dbase = 4 * kl;
#pragma unroll 4
      for (int kb = 0; kb < 32; kb++) {
        float4 ev[3];
#pragma unroll
        for (int j = 0; j < 3; j++)
          ev[j] = *(const float4*)&eS[(wr0 + 3 * rg + j) * 132 + 4 * kb];
#pragma unroll
        for (int x = 0; x < 4; x++) {
          const int dx = dbase + x;
          float4 vv = *(const float4*)&kv[dx * 128 + ((kb ^ (dx & 31)) << 2)];
#pragma unroll
          for (int j = 0; j < 3; j++) {
            acc[j][x] += ev[j].x * vv.x + ev[j].y * vv.y
                       + ev[j].z * vv.z + ev[j].w * vv.w;
          }
        }
      }
#pragma unroll
      for (int j = 0; j < 3; j++) {
        const int R = wr0 + 3 * rg + j;
        if (R < nact) {
          float* p = part + ((size_t)(bh * TOPU + R) * NCH + ch) * PSTRIDE;
          float4 o = make_float4(acc[j][0] * (1.0f / 64.0f), acc[j][1] * (1.0f / 64.0f),
                                 acc[j][2] * (1.0f / 64.0f), acc[j][3] * (1.0f / 64.0f));
          *(float4*)&p[4 * kl] = o;
        }
      }
    }
  }
}

// ---------------- update phase 2: combine valid chunks + write column ----------------
// 256 threads = 4 waves, one row per wave.
__global__ __launch_bounds__(256) void update_combine(const float* __restrict__ part,
                                                      const int* __restrict__ ssel_g,
                                                      float* __restrict__ out) {
  const int row = blockIdx.x * 4 + (threadIdx.x >> 6);   // 0..BH*TOPU-1
  if (row >= BH * TOPU) return;
  const int bh = row / TOPU;
  const int sel = ssel_g[row];
  const int d = threadIdx.x & 63;
  const int nv = sel / CHUNK + 1;
  const float* p = part + (size_t)row * NCH * PSTRIDE;

  float m = -INFINITY;
  for (int c = 0; c < nv; c++) m = fmaxf(m, p[c * PSTRIDE + 64]);

  float num = 0.0f, den = 0.0f;
  for (int c = 0; c < nv; c++) {
    float mc = p[c * PSTRIDE + 64];
    float wgt = expf(mc - m);
    num += wgt * p[c * PSTRIDE + d];
    den += wgt * p[c * PSTRIDE + 65];
  }
  out[((size_t)bh * D_ + d) * L_ + sel] = num / den;
}

extern "C" void kernel_launch(void* const* d_in, const int* in_sizes, int n_in,
                              void* d_out, int out_size, void* d_ws, size_t ws_size,
                              hipStream_t stream) {
  const float* q = (const float*)d_in[0];
  const float* k = (const float*)d_in[1];
  const float* v = (const float*)d_in[2];
  float* out = (float*)d_out;

  const size_t NT = (size_t)BH * L_ * D_;      // 8388608 floats per tensor
  float* kt = (float*)d_ws;                    // 32MB
  float* M  = kt + NT;                         // BH*L floats
  int* idx  = (int*)(M + (size_t)BH * L_);     // 4096*25 ints
  int* ssel = idx + L_ * U_PART;               // BH*45 ints (sorted desc per bh)
  float* qsel = (float*)(ssel + BH * TOPU);    // BH*45*64 floats
  float* part = qsel + (size_t)BH * TOPU * 64; // 1440*32*68 floats (~12.5 MB)

  uint32_t k2a, k2b;
#if JAX_THREEFRY_PARTITIONABLE
  tf2x32(0u, 42u, 0u, 1u, k2a, k2b);
#else
  uint32_t a0, a1, b0, b1;
  tf2x32(0u, 42u, 0u, 2u, a0, a1);
  tf2x32(0u, 42u, 1u, 3u, b0, b1);
  k2a = a1; k2b = b1;
#endif

  prep_kernel<<<dim3(L_ / 64, BH), 256, 0, stream>>>(k, kt, idx, k2a, k2b);
  m_cumsum_kernel<<<2560, 1024, 0, stream>>>(q, kt, idx, v, M, out);
  topk_kernel<<<BH, 256, 0, stream>>>(M, q, ssel, qsel);
  update_partial<<<BH * 16, 256, 0, stream>>>(qsel, k, v, ssel, part);
  update_combine<<<(BH * TOPU + 3) / 4, 256, 0, stream>>>(part, ssel, out);
}

// Round 16
// 149.212 us; speedup vs baseline: 1.1623x; 1.1623x over previous
//
#include <hip/hip_runtime.h>
#include <cstdint>

// Reference geometry (fixed problem)
constexpr int B_ = 4, H_ = 8, D_ = 64, L_ = 4096;
constexpr int BH = B_ * H_;          // 32
constexpr int U_PART = 25;           // FACTOR * ceil(log(64))
constexpr int TOPU = 45;             // FACTOR * ceil(log(4096))
constexpr int CHUNK = 128;           // keys per update chunk (LDS-staged)
constexpr int NCH = L_ / CHUNK;      // 32 chunks
constexpr int PSTRIDE = 68;          // acc[64], max, sum, pad to 16B-aligned stride

#define JAX_THREEFRY_PARTITIONABLE 1

// ---------------- Threefry-2x32 (exact JAX semantics) ----------------
__host__ __device__ inline void tf2x32(uint32_t k0, uint32_t k1,
                                       uint32_t x0, uint32_t x1,
                                       uint32_t& y0, uint32_t& y1) {
  const uint32_t ks2 = k0 ^ k1 ^ 0x1BD11BDAu;
  uint32_t v0 = x0 + k0, v1 = x1 + k1;
#define RND(r) { v0 += v1; v1 = (v1 << (r)) | (v1 >> (32 - (r))); v1 ^= v0; }
  RND(13) RND(15) RND(26) RND(6)
  v0 += k1; v1 += ks2 + 1u;
  RND(17) RND(29) RND(16) RND(24)
  v0 += ks2; v1 += k0 + 2u;
  RND(13) RND(15) RND(26) RND(6)
  v0 += k0; v1 += k1 + 3u;
  RND(17) RND(29) RND(16) RND(24)
  v0 += k1; v1 += ks2 + 4u;
  RND(13) RND(15) RND(26) RND(6)
  v0 += ks2; v1 += k0 + 5u;
#undef RND
  y0 = v0; y1 = v1;
}

// ---------------- prep: k transpose+scale + threefry idx ----------------
__global__ __launch_bounds__(256) void prep_kernel(
    const float* __restrict__ k, float* __restrict__ kt,
    int* __restrict__ idx, uint32_t k2a, uint32_t k2b) {
  const int bh = blockIdx.y;
  const int t = threadIdx.x;
#if JAX_THREEFRY_PARTITIONABLE
  {
    const int bid = bh * 64 + blockIdx.x;
    if (t < 50) {
      uint32_t y0, y1;
      const uint32_t i = (uint32_t)(bid * 50 + t);
      tf2x32(k2a, k2b, 0u, i, y0, y1);
      idx[bid * 50 + t] = (int)((y0 ^ y1) & 4095u);
    }
  }
#else
  {
    const int bid = bh * 64 + blockIdx.x;
    const int half = (L_ * U_PART) / 2;   // 51200
    if (t < 25) {
      uint32_t y0, y1;
      const int j = bid * 25 + t;
      tf2x32(k2a, k2b, (uint32_t)j, (uint32_t)(j + half), y0, y1);
      idx[j] = (int)(y0 & 4095u);
      idx[j + half] = (int)(y1 & 4095u);
    }
  }
#endif
  // k transpose + scale (1/64), float4 global both sides
  const int l0 = blockIdx.x * 64;
  __shared__ float tile[64][65];
  const float* s = k + (size_t)bh * D_ * L_ + l0;
  float* d = kt + (size_t)bh * L_ * D_;
  const int rhi = t >> 4, rlo = t & 15;
#pragma unroll
  for (int i = 0; i < 4; i++) {
    const int dd = i * 16 + rhi;
    float4 x = *(const float4*)&s[(size_t)dd * L_ + 4 * rlo];
    tile[dd][4 * rlo + 0] = x.x * (1.0f / 64.0f);
    tile[dd][4 * rlo + 1] = x.y * (1.0f / 64.0f);
    tile[dd][4 * rlo + 2] = x.z * (1.0f / 64.0f);
    tile[dd][4 * rlo + 3] = x.w * (1.0f / 64.0f);
  }
  __syncthreads();
#pragma unroll
  for (int i = 0; i < 4; i++) {
    const int ll = i * 16 + rhi;
    float4 o;
    o.x = tile[4 * rlo + 0][ll];
    o.y = tile[4 * rlo + 1][ll];
    o.z = tile[4 * rlo + 2][ll];
    o.w = tile[4 * rlo + 3][ll];
    *(float4*)&d[(size_t)(l0 + ll) * D_ + 4 * rlo] = o;
  }
}

// ---------------- DPP 16-lane butterfly helper (VALU, no DS pipe) ----------------
__device__ __forceinline__ float dpp_bcast_add16(float x) {
  int xi;
  xi = __builtin_amdgcn_mov_dpp(__float_as_int(x), 0x140, 0xF, 0xF, true);
  x += __int_as_float(xi);
  xi = __builtin_amdgcn_mov_dpp(__float_as_int(x), 0x141, 0xF, 0xF, true);
  x += __int_as_float(xi);
  xi = __builtin_amdgcn_mov_dpp(__float_as_int(x), 0x4E, 0xF, 0xF, true);
  x += __int_as_float(xi);
  xi = __builtin_amdgcn_mov_dpp(__float_as_int(x), 0xB1, 0xF, 0xF, true);
  x += __int_as_float(xi);
  return x;
}

// ---------------- M[b,h,l] = max_s QK - sum_s QK / 4096 ----------------
// r14's proven shape: 1024-thread block = 64 l's, one l per 16-lane group,
// one chain per thread, ~24 VGPR. XCD-swizzled (each XCD owns 4 bh).
__global__ __launch_bounds__(1024) void m_kernel(const float* __restrict__ qraw,
                                                 const float* __restrict__ kt,
                                                 const int* __restrict__ idx,
                                                 float* __restrict__ M) {
  const int t = threadIdx.x;
  const int xcd = blockIdx.x & 7;
  const int slot = blockIdx.x >> 3;            // 0..255
  const int bh = xcd * 4 + (slot >> 6);
  const int l0 = (slot & 63) * 64;
  const float* ktb = kt + (size_t)bh * L_ * D_;
  __shared__ float qs[64][65];
  {
    const float* s = qraw + (size_t)bh * D_ * L_ + l0;
    const int w = t >> 6, lane = t & 63;
#pragma unroll
    for (int j = 0; j < 4; j++) {
      const int d = j * 16 + w;
      qs[lane][d] = s[(size_t)d * L_ + lane] * (1.0f / 512.0f);
    }
  }
  __syncthreads();
  const int grp = t >> 4, gl = t & 15;         // 64 groups, one l each
  const int l = l0 + grp;
  const float4 ql = *(const float4*)&qs[grp][4 * gl];
  const int* ip = idx + (size_t)l * U_PART;
  float mx = -INFINITY, sm = 0.0f;
#pragma unroll 5
  for (int s2 = 0; s2 < U_PART; s2++) {
    const int ki = ip[s2];
    float4 kk = *(const float4*)(ktb + (size_t)ki * D_ + gl * 4);
    float p = ql.x * kk.x + ql.y * kk.y + ql.z * kk.z + ql.w * kk.w;
    p = dpp_bcast_add16(p);
    mx = fmaxf(mx, p);
    sm += p;
  }
  if (gl == 0) M[bh * L_ + l] = mx - sm * (1.0f / 4096.0f);
}

// ---------------- FUSED: topk (blocks 0..31, latency-bound) + cumsum (BW) ----------------
// topk blocks dispatched first (start immediately on 32 CUs); the 2048 cumsum
// blocks stream v->out on the remaining CUs concurrently. Complementary pairing:
// topk's footprint is tiny (128KB M per bh), so the v-stream can't thrash it.
__global__ __launch_bounds__(256) void topk_cumsum_kernel(
    const float* __restrict__ M, const float* __restrict__ qraw,
    const float* __restrict__ vraw,
    int* __restrict__ ssel_g, float* __restrict__ qsel,
    float* __restrict__ out) {
  const int bid = blockIdx.x;
  const int t = threadIdx.x;
  if (bid >= BH) {
    // ---- cumsum path: row = bid-32 (bh*64+d), 256 threads per row ----
    const int row = bid - BH;            // 0..2047
    const float* src = vraw + (size_t)row * L_;
    float* dst = out + (size_t)row * L_;
    float vals[16];
    const float4* s4 = (const float4*)(src + t * 16);
#pragma unroll
    for (int i = 0; i < 4; i++) {
      float4 x = s4[i];
      vals[4 * i + 0] = x.x; vals[4 * i + 1] = x.y;
      vals[4 * i + 2] = x.z; vals[4 * i + 3] = x.w;
    }
    float run = 0.0f;
#pragma unroll
    for (int i = 0; i < 16; i++) { run += vals[i] * (1.0f / 64.0f); vals[i] = run; }
    float x = run;
#pragma unroll
    for (int off = 1; off < 64; off <<= 1) {
      float y = __shfl_up(x, off, 64);
      if ((t & 63) >= off) x += y;
    }
    __shared__ float wtot[4];
    if ((t & 63) == 63) wtot[t >> 6] = x;
    __syncthreads();
    float woff = 0.0f;
    for (int w = 0; w < (t >> 6); w++) woff += wtot[w];
    const float excl = x - run + woff;
#pragma unroll
    for (int i = 0; i < 16; i++) vals[i] += excl;
    float4* d4 = (float4*)(dst + t * 16);
#pragma unroll
    for (int i = 0; i < 4; i++)
      d4[i] = make_float4(vals[4 * i], vals[4 * i + 1], vals[4 * i + 2], vals[4 * i + 3]);
    return;
  }
  // ---- topk path: bh = bid ----
  const int bh = bid;
  const int w = t >> 6, lane = t & 63;
  const float* Mb = M + (size_t)bh * L_;
  const int base = w * 1024 + lane;
  uint32_t v[16];
#pragma unroll
  for (int j = 0; j < 16; j++) {
    uint32_t b = __float_as_uint(Mb[base + j * 64]);
    v[j] = b ^ ((b & 0x80000000u) ? 0xFFFFFFFFu : 0x80000000u);
  }
  __shared__ unsigned long long red[4];
  __shared__ int picks[TOPU];
  __shared__ int ssorted[TOPU];
  for (int it = 0; it < TOPU; it++) {
    unsigned long long best = 0ull;
#pragma unroll
    for (int j = 0; j < 16; j++) {
      unsigned long long key = ((unsigned long long)v[j] << 32)
                             | (uint32_t)(L_ - 1 - (base + j * 64));
      best = (key > best) ? key : best;
    }
#pragma unroll
    for (int off = 32; off; off >>= 1) {
      unsigned long long o = __shfl_xor(best, off, 64);
      best = (o > best) ? o : best;
    }
    if (lane == 0) red[w] = best;
    __syncthreads();
    unsigned long long g = red[0];
    if (red[1] > g) g = red[1];
    if (red[2] > g) g = red[2];
    if (red[3] > g) g = red[3];
    const int bi = L_ - 1 - (int)(g & 0xFFFFFFFFu);
    if (t == 0) picks[it] = bi;
    if ((bi >> 10) == w && (bi & 63) == lane) {
      const int slot = (bi >> 6) & 15;
#pragma unroll
      for (int j = 0; j < 16; j++) if (slot == j) v[j] = 0u;
    }
    __syncthreads();
  }
  if (t < TOPU) {
    int my = picks[t];
    int rank = 0;
    for (int j = 0; j < TOPU; j++) rank += (picks[j] > my);
    ssorted[rank] = my;
  }
  __syncthreads();
  if (t < TOPU) ssel_g[bh * TOPU + t] = ssorted[t];
  // gather selected q rows (scaled): qsel[bh][r][d] = q[bh, d, sel_r] / 512
  const float* qb = qraw + (size_t)bh * D_ * L_;
  for (int e = t; e < TOPU * 64; e += 256) {
    const int r = e >> 6, d = e & 63;
    qsel[((size_t)bh * TOPU + r) * 64 + e % 64] =
        qb[(size_t)d * L_ + ssorted[r]] * (1.0f / 512.0f);
  }
}

// ---------------- update phase 1: register-tiled GEMM per (bh, chunk-pair) ----------------
// Q from qsel (coalesced); K staged linear [d][key] from raw k; V staged [d][key]
// with granule-XOR swizzle from raw v. PV dots along the key axis. XCD-swizzled.
__global__ __launch_bounds__(256) void update_partial(const float* __restrict__ qsel,
                                                      const float* __restrict__ kraw,
                                                      const float* __restrict__ vraw,
                                                      const int* __restrict__ ssel_g,
                                                      float* __restrict__ part) {
  const int xcd = blockIdx.x & 7;
  const int slot = blockIdx.x >> 3;   // 0..63
  const int bh = xcd * 4 + (slot >> 4);
  const int ch0 = slot & 15;
  const int t = threadIdx.x;
  const int w = t >> 6, lane = t & 63;
  const int kl = lane & 15, rg = lane >> 4;

  __shared__ float kv[CHUNK * 64];    // 32KB: kS[d][128] linear, then vS[d][128] swizzled
  __shared__ float qs[48 * 68];       // padded stride 68
  __shared__ float eS[48 * 132];      // padded stride 132
  __shared__ int ssel[48];

  if (t < 48) ssel[t] = (t < TOPU) ? ssel_g[bh * TOPU + t] : -1;
  __syncthreads();

  // stage Q from qsel: 48 rows x 64 d (rows 45..47 zero)
#pragma unroll
  for (int j = 0; j < 3; j++) {
    int it = t + 256 * j;             // 0..767
    int rr = it >> 4, dc = it & 15;
    float4 qv = make_float4(0.f, 0.f, 0.f, 0.f);
    if (rr < TOPU) qv = *(const float4*)&qsel[((size_t)bh * TOPU + rr) * 64 + 4 * dc];
    *(float4*)&qs[rr * 68 + 4 * dc] = qv;
  }

  for (int pass = 0; pass < 2; pass++) {
    const int ch = pass ? (31 - ch0) : ch0;
    const int k0 = ch * CHUNK;
    int lo = 0, hi = TOPU;
    while (lo < hi) { int mid = (lo + hi) >> 1; if (ssel[mid] >= k0) lo = mid + 1; else hi = mid; }
    const int nact = lo;
    if (nact == 0) continue;          // uniform across block

    __syncthreads();
    // stage K: kv[d*128 + key] = kraw[bh, d, k0+key]  (linear, conflict-free)
    const float* kb = kraw + (size_t)bh * D_ * L_ + k0;
#pragma unroll
    for (int j = 0; j < 8; j++) {
      int e4 = 4 * (t + 256 * j);
      int d = e4 >> 7, key = e4 & 127;
      *(float4*)&kv[e4] = *(const float4*)&kb[(size_t)d * L_ + key];
    }
    __syncthreads();

    const int wr0 = 12 * w;
    if (wr0 < nact) {
      float s[3][8];
#pragma unroll
      for (int j = 0; j < 3; j++)
#pragma unroll
        for (int x = 0; x < 8; x++) s[j][x] = 0.f;
#pragma unroll 8
      for (int d = 0; d < 64; d++) {
        float4 ka = *(const float4*)&kv[d * 128 + 4 * kl];
        float4 kb2 = *(const float4*)&kv[d * 128 + 64 + 4 * kl];
#pragma unroll
        for (int j = 0; j < 3; j++) {
          float qd = qs[(wr0 + 3 * rg + j) * 68 + d];
          s[j][0] += qd * ka.x;  s[j][1] += qd * ka.y;
          s[j][2] += qd * ka.z;  s[j][3] += qd * ka.w;
          s[j][4] += qd * kb2.x; s[j][5] += qd * kb2.y;
          s[j][6] += qd * kb2.z; s[j][7] += qd * kb2.w;
        }
      }
#pragma unroll
      for (int j = 0; j < 3; j++) {
        const int R = wr0 + 3 * rg + j;
        const int sel = ssel[R];
        float mx = -INFINITY;
#pragma unroll
        for (int x = 0; x < 8; x++) {
          int kg = k0 + 4 * kl + (x < 4 ? x : 60 + x);   // keys 4kl+{0..3}, 64+4kl+{0..3}
          s[j][x] *= (1.0f / 32768.0f);
          if (kg > sel) s[j][x] = -INFINITY;
          mx = fmaxf(mx, s[j][x]);
        }
        mx = fmaxf(mx, __shfl_xor(mx, 1, 64));
        mx = fmaxf(mx, __shfl_xor(mx, 2, 64));
        mx = fmaxf(mx, __shfl_xor(mx, 4, 64));
        mx = fmaxf(mx, __shfl_xor(mx, 8, 64));
        float e[8], sm = 0.f;
#pragma unroll
        for (int x = 0; x < 8; x++) { e[x] = expf(s[j][x] - mx); sm += e[x]; }
        sm += __shfl_xor(sm, 1, 64);
        sm += __shfl_xor(sm, 2, 64);
        sm += __shfl_xor(sm, 4, 64);
        sm += __shfl_xor(sm, 8, 64);
        *(float4*)&eS[R * 132 + 4 * kl] = make_float4(e[0], e[1], e[2], e[3]);
        *(float4*)&eS[R * 132 + 64 + 4 * kl] = make_float4(e[4], e[5], e[6], e[7]);
        if (kl == 0 && R < nact) {
          float* p = part + ((size_t)(bh * TOPU + R) * NCH + ch) * PSTRIDE;
          p[64] = mx; p[65] = sm;
        }
      }
    }
    __syncthreads();
    // stage V: kv[d*128 + ((kq ^ (d&31))<<2)] = vraw[bh, d, k0+4kq..+3]
    const float* vb = vraw + (size_t)bh * D_ * L_ + k0;
#pragma unroll
    for (int j = 0; j < 8; j++) {
      int e4 = 4 * (t + 256 * j);
      int d = e4 >> 7, kq = (e4 & 127) >> 2;
      float4 vv = *(const float4*)&vb[(size_t)d * L_ + 4 * kq];
      *(float4*)&kv[d * 128 + ((kq ^ (d & 31)) << 2)] = vv;
    }
    __syncthreads();
    if (wr0 < nact) {
      float acc[3][4];
#pragma unroll
      for (int j = 0; j < 3; j++)
#pragma unroll
        for (int x = 0; x < 4; x++) acc[j][x] = 0.f;
      const int dbase = 4 * kl;
#pragma unroll 4
      for (int kb = 0; kb < 32; kb++) {
        float4 ev[3];
#pragma unroll
        for (int j = 0; j < 3; j++)
          ev[j] = *(const float4*)&eS[(wr0 + 3 * rg + j) * 132 + 4 * kb];
#pragma unroll
        for (int x = 0; x < 4; x++) {
          const int dx = dbase + x;
          float4 vv = *(const float4*)&kv[dx * 128 + ((kb ^ (dx & 31)) << 2)];
#pragma unroll
          for (int j = 0; j < 3; j++) {
            acc[j][x] += ev[j].x * vv.x + ev[j].y * vv.y
                       + ev[j].z * vv.z + ev[j].w * vv.w;
          }
        }
      }
#pragma unroll
      for (int j = 0; j < 3; j++) {
        const int R = wr0 + 3 * rg + j;
        if (R < nact) {
          float* p = part + ((size_t)(bh * TOPU + R) * NCH + ch) * PSTRIDE;
          float4 o = make_float4(acc[j][0] * (1.0f / 64.0f), acc[j][1] * (1.0f / 64.0f),
                                 acc[j][2] * (1.0f / 64.0f), acc[j][3] * (1.0f / 64.0f));
          *(float4*)&p[4 * kl] = o;
        }
      }
    }
  }
}

// ---------------- update phase 2: combine valid chunks + write column ----------------
// 256 threads = 4 waves, one row per wave.
__global__ __launch_bounds__(256) void update_combine(const float* __restrict__ part,
                                                      const int* __restrict__ ssel_g,
                                                      float* __restrict__ out) {
  const int row = blockIdx.x * 4 + (threadIdx.x >> 6);   // 0..BH*TOPU-1
  if (row >= BH * TOPU) return;
  const int bh = row / TOPU;
  const int sel = ssel_g[row];
  const int d = threadIdx.x & 63;
  const int nv = sel / CHUNK + 1;
  const float* p = part + (size_t)row * NCH * PSTRIDE;

  float m = -INFINITY;
  for (int c = 0; c < nv; c++) m = fmaxf(m, p[c * PSTRIDE + 64]);

  float num = 0.0f, den = 0.0f;
  for (int c = 0; c < nv; c++) {
    float mc = p[c * PSTRIDE + 64];
    float wgt = expf(mc - m);
    num += wgt * p[c * PSTRIDE + d];
    den += wgt * p[c * PSTRIDE + 65];
  }
  out[((size_t)bh * D_ + d) * L_ + sel] = num / den;
}

extern "C" void kernel_launch(void* const* d_in, const int* in_sizes, int n_in,
                              void* d_out, int out_size, void* d_ws, size_t ws_size,
                              hipStream_t stream) {
  const float* q = (const float*)d_in[0];
  const float* k = (const float*)d_in[1];
  const float* v = (const float*)d_in[2];
  float* out = (float*)d_out;

  const size_t NT = (size_t)BH * L_ * D_;      // 8388608 floats per tensor
  float* kt = (float*)d_ws;                    // 32MB
  float* M  = kt + NT;                         // BH*L floats
  int* idx  = (int*)(M + (size_t)BH * L_);     // 4096*25 ints
  int* ssel = idx + L_ * U_PART;               // BH*45 ints (sorted desc per bh)
  float* qsel = (float*)(ssel + BH * TOPU);    // BH*45*64 floats
  float* part = qsel + (size_t)BH * TOPU * 64; // 1440*32*68 floats (~12.5 MB)

  uint32_t k2a, k2b;
#if JAX_THREEFRY_PARTITIONABLE
  tf2x32(0u, 42u, 0u, 1u, k2a, k2b);
#else
  uint32_t a0, a1, b0, b1;
  tf2x32(0u, 42u, 0u, 2u, a0, a1);
  tf2x32(0u, 42u, 1u, 3u, b0, b1);
  k2a = a1; k2b = b1;
#endif

  prep_kernel<<<dim3(L_ / 64, BH), 256, 0, stream>>>(k, kt, idx, k2a, k2b);
  m_kernel<<<BH * 64, 1024, 0, stream>>>(q, kt, idx, M);
  topk_cumsum_kernel<<<BH + BH * D_, 256, 0, stream>>>(M, q, v, ssel, qsel, out);
  update_partial<<<BH * 16, 256, 0, stream>>>(qsel, k, v, ssel, part);
  update_combine<<<(BH * TOPU + 3) / 4, 256, 0, stream>>>(part, ssel, out);
}